// Round 4
// baseline (195.180 us; speedup 1.0000x reference)
//
#include <hip/hip_runtime.h>
#include <cstdint>
#include <cstddef>

// Problem constants (fixed by the reference)
#define B_DIM 8192
#define C_DIM 4096
#define F_DIM 1024
#define O_DIM 10
#define NSLICE 16  // C_DIM / 256 partial slices
#define BK 32      // K-tile depth
#define NT 32      // F_DIM / BK

typedef __attribute__((ext_vector_type(8))) __bf16 bf16x8;
typedef __attribute__((ext_vector_type(8))) unsigned short ushort8;
typedef __attribute__((ext_vector_type(4))) float f32x4;
typedef __attribute__((ext_vector_type(4))) unsigned int u32x4;

// ---------------------------------------------------------------------------
// fp32 -> bf16 round-to-nearest-even
__device__ __forceinline__ unsigned short f2bf(float f) {
  unsigned int u = __builtin_bit_cast(unsigned int, f);
  u += 0x7fffu + ((u >> 16) & 1u);
  return (unsigned short)(u >> 16);
}

// ---------------------------------------------------------------------------
// Wave-per-row prep: rows [0,B_DIM) = x, rows [B_DIM, B_DIM+C_DIM) = loc.
// Converts fp32 row -> bf16 and computes fp32 ||row||^2. No LDS, no barrier.
__global__ __launch_bounds__(512) void prep_merged(
    const float* __restrict__ x, const float* __restrict__ loc,
    unsigned short* __restrict__ xb, unsigned short* __restrict__ locb,
    float* __restrict__ x2, float* __restrict__ c2) {
  const int wave = threadIdx.x >> 6;
  const int lane = threadIdx.x & 63;
  const int row = blockIdx.x * 8 + wave;
  const float* src;
  unsigned short* dst;
  float* nrm;
  if (row < B_DIM) {
    src = x + (size_t)row * F_DIM;
    dst = xb + (size_t)row * F_DIM;
    nrm = x2 + row;
  } else {
    const int r = row - B_DIM;
    src = loc + (size_t)r * F_DIM;
    dst = locb + (size_t)r * F_DIM;
    nrm = c2 + r;
  }
  float ss = 0.f;
#pragma unroll
  for (int i = 0; i < 4; ++i) {
    const float4 v = reinterpret_cast<const float4*>(src)[lane + 64 * i];
    ss += v.x * v.x + v.y * v.y + v.z * v.z + v.w * v.w;
    ushort4 o;
    o.x = f2bf(v.x); o.y = f2bf(v.y); o.z = f2bf(v.z); o.w = f2bf(v.w);
    reinterpret_cast<ushort4*>(dst)[lane + 64 * i] = o;
  }
#pragma unroll
  for (int m = 1; m <= 32; m <<= 1) ss += __shfl_xor(ss, m, 64);
  if (lane == 0) *nrm = ss;
}

// ---------------------------------------------------------------------------
// Fused: S = loc_bf16 @ x_bf16^T (MFMA), phi = exp(-sqrt(max(c2+x2-2S,0))/scale),
// P[slice][b][o] = sum_{c in 256-slice} phi[c][b] * w[o][c]   (no atomics).
//
// Tile: 256 c (M) x 256 b (N), BK=32; 512 threads = 8 waves in (c-half 2) x
// (b-quarter 4); each wave 128x64 via 8x4 grid of 16x16x32 MFMAs.
//
// R2 POST-MORTEM (recorded): launch_bounds(512,4) caps the unified VGPR+AGPR
// file at 128/wave < the 128-reg accumulator + fragments -> scratch spill
// (VGPR_Count 64, WRITE_SIZE 2.48 GB, 826us). This tile shape REQUIRES the
// 256-reg budget => 2 waves/SIMD is the occupancy ceiling. Do not retry.
//
// R3 POST-MORTEM (recorded): R0 (depth-1 drain), R1 (8-phase counted), R3
// (depth-3 counted) all ~105-109us / 26% MfmaUtil. Cause: fragment reads were
// plain C++ LDS loads; the backend waitcnt pass must order ds_read against
// in-flight global_load_lds (a VMEM op that WRITES LDS) and cannot prove
// disjointness, so it inserts a vmcnt drain before the reads -> every
// schedule degenerates to depth-0 (waits on the JUST-issued prefetch).
//
// R4 LEVER: fragment reads as inline-asm ds_read_b128 (opaque to the waitcnt
// pass) + explicit "s_waitcnt lgkmcnt(0)" + sched_barrier(0) (rule #18: MFMA
// hoists past asm waitcnt otherwise). Our counted vmcnt(8) then finally
// governs: tiles t+1,t+2 stay in flight, issued ~2 computes before their
// wait. This is the m201/m218 8-phase-template detail (their subtile reads
// are asm) that R1's port missed.
//
// Safety: each wave's ds_reads of buf t&3 retire at its own lgkmcnt(0)
// before it reaches the next WAITB barrier => after that barrier no reader
// of buf (t-1)&3 exists, so ISSUE(t+3) overwriting it is race-free. vmcnt
// counts 4 loads/tile/thread, in-order retirement => vmcnt(8) = tile t
// landed. Peel: vm(8),vm(8),vm(4),vm(0).
//
// LDS swizzle (4 slots of 16B per 64B row): phys_slot = k_chunk ^ ((row>>1)&3).
// Writer: global_load_lds dest is linear (HW adds lane*16); the SOURCE k-chunk
// is pre-swizzled per-lane: kcol = ((lane&3) ^ ((lane>>3)&3))*8. Reader adds
// the same involution: slot = (quad ^ ((n15>>1)&3))*8. 2-way bank aliasing =
// free (m136). Verified numerically R2/R3 (absmax unchanged).
//
// XCD swizzle: blockIdx&7 = XCD; c-neighbors (2g,2g+1) sharing a b-tile are
// adjacent ids -> co-resident on one XCD -> L2 captures the pair.
__global__ __launch_bounds__(512, 2) void rbf_fused(
    const unsigned short* __restrict__ locb,  // [C_DIM][F_DIM] bf16 bits
    const unsigned short* __restrict__ xb,    // [B_DIM][F_DIM] bf16 bits
    const float* __restrict__ c2,             // [C_DIM]
    const float* __restrict__ x2,             // [B_DIM]
    const float* __restrict__ scale,          // [C_DIM]
    const float* __restrict__ w,              // [O_DIM][C_DIM]
    float* __restrict__ P) {                  // [NSLICE][B_DIM][O_DIM]
  extern __shared__ unsigned short smem[];
  unsigned short* As = smem;           // 4 x 256x32 = 64 KB (8192 elems/buf)
  unsigned short* Bs = smem + 32768;   // 4 x 256x32 = 64 KB

  const int tid = threadIdx.x;
  const int wave = tid >> 6;
  const int lane = tid & 63;
  const int quad = lane >> 4;
  const int n15 = lane & 15;

  // XCD-aware mapping: g = XCD, cIdx in {2g, 2g+1} fastest, then bIdx.
  const int id = blockIdx.x;
  const int g = id & 7;
  const int j = id >> 3;
  const int cIdx = (g << 1) + (j & 1);  // 0..15
  const int bIdx = j >> 1;              // 0..31
  const int cBase = cIdx << 8;
  const int bBase = bIdx << 8;

  const int wch = wave >> 2;  // c-half 0/1
  const int bq = wave & 3;    // b-quarter 0..3
  const int wcc = wch * 128;  // wave centroid offset in tile
  const int wbb = bq * 64;    // wave batch offset in tile

  float x2v[4];
#pragma unroll
  for (int tj = 0; tj < 4; ++tj) x2v[tj] = x2[bBase + wbb + tj * 16 + n15];

  // Staging: per matrix per tile 16 KB = 2 instructions/thread; instruction c
  // covers rows c*128..c*128+127: row = c*128 + wave*16 + (lane>>2),
  // slot = lane&3. LDS dest base (wave-uniform; HW adds lane*16B):
  // c*4096 + wave*512 elems. Global source pre-swizzled by the slot involution.
  const int kcol = (((lane & 3) ^ ((lane >> 3) & 3)) << 3);  // bf16 elems
  const int rsw = ((quad ^ ((n15 >> 1) & 3)) << 3);          // reader slot elems

  const unsigned short* aPtr[2];
  const unsigned short* bPtr[2];
#pragma unroll
  for (int c = 0; c < 2; ++c) {
    const int row = c * 128 + wave * 16 + (lane >> 2);
    aPtr[c] = locb + (size_t)(cBase + row) * F_DIM + kcol;
    bPtr[c] = xb + (size_t)(bBase + row) * F_DIM + kcol;
  }

  // Per-thread LDS byte offsets of fragment (ti=0 / tj=0, buf 0). AS3 cast
  // yields the raw LDS offset (32-bit) for the asm ds_read address operand.
  const unsigned aBaseOff = (unsigned)(size_t)(
      const __attribute__((address_space(3))) void*)&As[(wcc + n15) * 32 + rsw];
  const unsigned bBaseOff = (unsigned)(size_t)(
      const __attribute__((address_space(3))) void*)&Bs[(wbb + n15) * 32 + rsw];

  // Per-thread per-tile: 4 loads (2 A + 2 B) -> vmcnt counts 4/tile.
  // Issue order within ISSUE is fixed (A0,B0,A1,B1) and tile-ordered across
  // calls, so s_waitcnt vmcnt(4*k) retires whole oldest tiles.
#define ISSUE(p, t)                                                            \
  do {                                                                         \
    _Pragma("unroll") for (int c_ = 0; c_ < 2; ++c_) {                         \
      __builtin_amdgcn_global_load_lds(                                        \
          (const __attribute__((address_space(1))) void*)(aPtr[c_] + (t)*BK),  \
          (__attribute__((address_space(3))) void*)&As[(p)*8192 + c_ * 4096 +  \
                                                       wave * 512],            \
          16, 0, 0);                                                           \
      __builtin_amdgcn_global_load_lds(                                        \
          (const __attribute__((address_space(1))) void*)(bPtr[c_] + (t)*BK),  \
          (__attribute__((address_space(3))) void*)&Bs[(p)*8192 + c_ * 4096 +  \
                                                       wave * 512],            \
          16, 0, 0);                                                           \
    }                                                                          \
  } while (0)

  // 12 asm ds_read_b128 (opaque to waitcnt pass -> no auto vmcnt drain),
  // explicit lgkmcnt(0) + sched_barrier(0) fence (rule #18), 32 MFMA.
  // Fragment strides: buf p = p*16384 B, ti/tj = 1024 B (16 rows x 64 B).
#define COMPUTE(p)                                                             \
  do {                                                                         \
    u32x4 ar[8], br[4];                                                        \
    const unsigned ap_ = aBaseOff + (unsigned)(p)*16384u;                      \
    const unsigned bp_ = bBaseOff + (unsigned)(p)*16384u;                      \
    _Pragma("unroll") for (int ti_ = 0; ti_ < 8; ++ti_)                        \
        asm volatile("ds_read_b128 %0, %1"                                     \
                     : "=v"(ar[ti_])                                           \
                     : "v"(ap_ + (unsigned)(ti_ * 1024)));                     \
    _Pragma("unroll") for (int tj_ = 0; tj_ < 4; ++tj_)                        \
        asm volatile("ds_read_b128 %0, %1"                                     \
                     : "=v"(br[tj_])                                           \
                     : "v"(bp_ + (unsigned)(tj_ * 1024)));                     \
    asm volatile("s_waitcnt lgkmcnt(0)" ::: "memory");                         \
    __builtin_amdgcn_sched_barrier(0);                                         \
    __builtin_amdgcn_s_setprio(1);                                             \
    _Pragma("unroll") for (int ti_ = 0; ti_ < 8; ++ti_)                        \
        _Pragma("unroll") for (int tj_ = 0; tj_ < 4; ++tj_)                    \
            acc[ti_][tj_] = __builtin_amdgcn_mfma_f32_16x16x32_bf16(           \
                __builtin_bit_cast(bf16x8, ar[ti_]),                           \
                __builtin_bit_cast(bf16x8, br[tj_]), acc[ti_][tj_], 0, 0, 0);  \
    __builtin_amdgcn_s_setprio(0);                                             \
  } while (0)

  // Counted wait + barrier: wave's own oldest loads (the tile about to be
  // read) retired before the barrier; N newest stay in flight.
#define WAITB(n) asm volatile("s_waitcnt vmcnt(" #n ")\ns_barrier" ::: "memory")

  f32x4 acc[8][4];
  const f32x4 zero = {0.f, 0.f, 0.f, 0.f};
#pragma unroll
  for (int i = 0; i < 8; ++i)
#pragma unroll
    for (int jj = 0; jj < 4; ++jj) acc[i][jj] = zero;

  // Depth-3 pipeline prologue: tiles 0,1,2 -> bufs 0,1,2.
  ISSUE(0, 0);
  ISSUE(1, 1);
  ISSUE(2, 2);
  for (int t = 0; t < 29; ++t) {
    WAITB(8);                    // tile t landed; t+1,t+2 stay in flight
    ISSUE((t + 3) & 3, t + 3);   // overwrites buf (t-1)&3: readers retired
    COMPUTE(t & 3);
  }
  WAITB(8);
  COMPUTE(1);  // t = 29
  WAITB(4);
  COMPUTE(2);  // t = 30
  WAITB(0);
  COMPUTE(3);  // t = 31
  __syncthreads();  // all waves done reading LDS before epilogue reuse

  // ---- epilogue ----
  // acc[ti][tj][r]: c_local = wcc+ti*16+quad*4+r, b_local = wbb+tj*16+n15.
  // Stage w / c2 / (-1/scale) into the dead As region (64 KB avail).
  float* wlds = reinterpret_cast<float*>(As);  // [O_DIM*256] = 10 KB
  float* c2l = wlds + O_DIM * 256;             // [256]
  float* nisl = c2l + 256;                     // [256]
  for (int i = tid; i < O_DIM * 256; i += 512)
    wlds[i] = w[(i >> 8) * C_DIM + cBase + (i & 255)];
  if (tid < 256) {
    c2l[tid] = c2[cBase + tid];
    nisl[tid] = -1.0f / scale[cBase + tid];
  }
  __syncthreads();

  float partial[4][O_DIM];
#pragma unroll
  for (int tj = 0; tj < 4; ++tj)
#pragma unroll
    for (int o = 0; o < O_DIM; ++o) partial[tj][o] = 0.f;

#pragma unroll
  for (int ti = 0; ti < 8; ++ti) {
    const int clq = wcc + ti * 16 + quad * 4;
    const f32x4 c24 = *(const f32x4*)&c2l[clq];
    const f32x4 ns4 = *(const f32x4*)&nisl[clq];
    float phi[4][4];  // [tj][r]
#pragma unroll
    for (int tj = 0; tj < 4; ++tj)
#pragma unroll
      for (int r = 0; r < 4; ++r) {
        const float s = acc[ti][tj][r];
        const float sq = fmaxf(x2v[tj] + c24[r] - 2.0f * s, 0.0f);
        phi[tj][r] = __expf(sqrtf(sq) * ns4[r]);
      }
#pragma unroll
    for (int o = 0; o < O_DIM; ++o) {
      const f32x4 w4 = *(const f32x4*)&wlds[o * 256 + clq];
#pragma unroll
      for (int tj = 0; tj < 4; ++tj)
#pragma unroll
        for (int r = 0; r < 4; ++r)
          partial[tj][o] = fmaf(phi[tj][r], w4[r], partial[tj][o]);
    }
  }

  // reduce over the 4 quads (lanes ^16, ^32 share the same batch index)
#pragma unroll
  for (int tj = 0; tj < 4; ++tj)
#pragma unroll
    for (int o = 0; o < O_DIM; ++o) {
      float v = partial[tj][o];
      v += __shfl_xor(v, 16, 64);
      v += __shfl_xor(v, 32, 64);
      partial[tj][o] = v;
    }

  // Cross-wave (c-halves) reduce via LDS (alias dead Bs), then store.
  float* red = reinterpret_cast<float*>(Bs);  // 2560 floats, region is dead
  if (wch == 0 && quad == 0) {
#pragma unroll
    for (int tj = 0; tj < 4; ++tj)
#pragma unroll
      for (int o = 0; o < O_DIM; ++o)
        red[(wbb + tj * 16 + n15) * O_DIM + o] = partial[tj][o];
  }
  __syncthreads();
  if (wch == 1 && quad == 0) {
#pragma unroll
    for (int tj = 0; tj < 4; ++tj)
#pragma unroll
      for (int o = 0; o < O_DIM; ++o)
        red[(wbb + tj * 16 + n15) * O_DIM + o] += partial[tj][o];
  }
  __syncthreads();
  float* Pdst = P + (size_t)cIdx * (B_DIM * O_DIM) + (size_t)bBase * O_DIM;
  for (int i = tid; i < 256 * O_DIM; i += 512) Pdst[i] = red[i];
}

// ---------------------------------------------------------------------------
// out[b][o] = sum_k P[k][b][o]
__global__ __launch_bounds__(256) void reduce_partials(const float* __restrict__ P,
                                                       float* __restrict__ out) {
  const int i = blockIdx.x * 256 + threadIdx.x;  // 0 .. B_DIM*O_DIM-1
  float s = 0.f;
#pragma unroll
  for (int k = 0; k < NSLICE; ++k) s += P[(size_t)k * (B_DIM * O_DIM) + i];
  out[i] = s;
}

// ---------------------------------------------------------------------------
extern "C" void kernel_launch(void* const* d_in, const int* in_sizes, int n_in,
                              void* d_out, int out_size, void* d_ws, size_t ws_size,
                              hipStream_t stream) {
  const float* x = (const float*)d_in[0];      // [8192,1024]
  const float* loc = (const float*)d_in[1];    // [4096,1024]
  const float* scale = (const float*)d_in[2];  // [4096]
  const float* w = (const float*)d_in[3];      // [10,4096]
  float* out = (float*)d_out;                  // [8192,10]

  // workspace layout (~30.3 MB)
  char* ws = (char*)d_ws;
  unsigned short* xb = (unsigned short*)(ws);                              // 16 MB
  unsigned short* locb = (unsigned short*)(ws + (size_t)16 * 1024 * 1024); // 8 MB
  float* x2 = (float*)(ws + (size_t)24 * 1024 * 1024);                    // 32 KB
  float* c2 = (float*)(ws + (size_t)24 * 1024 * 1024 + 64 * 1024);        // 16 KB
  float* P = (float*)(ws + (size_t)25 * 1024 * 1024);                     // 5.24 MB

  // 128 KB dynamic LDS (static cap is 64 KB). Host-side attribute set;
  // idempotent, not a stream op — safe under graph capture.
  hipFuncSetAttribute((const void*)rbf_fused,
                      hipFuncAttributeMaxDynamicSharedMemorySize, 131072);

  prep_merged<<<(B_DIM + C_DIM) / 8, 512, 0, stream>>>(x, loc, xb, locb, x2, c2);

  rbf_fused<<<NSLICE * 32, 512, 131072, stream>>>(locb, xb, c2, x2, scale, w, P);

  reduce_partials<<<(B_DIM * O_DIM) / 256, 256, 0, stream>>>(P, out);
}

// Round 5
// 189.879 us; speedup vs baseline: 1.0279x; 1.0279x over previous
//
#include <hip/hip_runtime.h>
#include <cstdint>
#include <cstddef>

// Problem constants (fixed by the reference)
#define B_DIM 8192
#define C_DIM 4096
#define F_DIM 1024
#define O_DIM 10
#define NSLICE 16  // C_DIM / 256 partial slices
#define BK 32      // K-tile depth
#define NT 32      // F_DIM / BK

typedef __attribute__((ext_vector_type(8))) __bf16 bf16x8;
typedef __attribute__((ext_vector_type(8))) unsigned short ushort8;
typedef __attribute__((ext_vector_type(4))) float f32x4;
typedef __attribute__((ext_vector_type(4))) unsigned int u32x4;

// ---------------------------------------------------------------------------
// fp32 -> bf16 round-to-nearest-even
__device__ __forceinline__ unsigned short f2bf(float f) {
  unsigned int u = __builtin_bit_cast(unsigned int, f);
  u += 0x7fffu + ((u >> 16) & 1u);
  return (unsigned short)(u >> 16);
}

// ---------------------------------------------------------------------------
// Wave-per-row prep: rows [0,B_DIM) = x, rows [B_DIM, B_DIM+C_DIM) = loc.
// Converts fp32 row -> bf16 and computes fp32 ||row||^2. No LDS, no barrier.
__global__ __launch_bounds__(512) void prep_merged(
    const float* __restrict__ x, const float* __restrict__ loc,
    unsigned short* __restrict__ xb, unsigned short* __restrict__ locb,
    float* __restrict__ x2, float* __restrict__ c2) {
  const int wave = threadIdx.x >> 6;
  const int lane = threadIdx.x & 63;
  const int row = blockIdx.x * 8 + wave;
  const float* src;
  unsigned short* dst;
  float* nrm;
  if (row < B_DIM) {
    src = x + (size_t)row * F_DIM;
    dst = xb + (size_t)row * F_DIM;
    nrm = x2 + row;
  } else {
    const int r = row - B_DIM;
    src = loc + (size_t)r * F_DIM;
    dst = locb + (size_t)r * F_DIM;
    nrm = c2 + r;
  }
  float ss = 0.f;
#pragma unroll
  for (int i = 0; i < 4; ++i) {
    const float4 v = reinterpret_cast<const float4*>(src)[lane + 64 * i];
    ss += v.x * v.x + v.y * v.y + v.z * v.z + v.w * v.w;
    ushort4 o;
    o.x = f2bf(v.x); o.y = f2bf(v.y); o.z = f2bf(v.z); o.w = f2bf(v.w);
    reinterpret_cast<ushort4*>(dst)[lane + 64 * i] = o;
  }
#pragma unroll
  for (int m = 1; m <= 32; m <<= 1) ss += __shfl_xor(ss, m, 64);
  if (lane == 0) *nrm = ss;
}

// ---------------------------------------------------------------------------
// Fused: S = loc_bf16 @ x_bf16^T (MFMA), phi = exp(-sqrt(max(c2+x2-2S,0))/scale),
// P[slice][b][o] = sum_{c in 256-slice} phi[c][b] * w[o][c]   (no atomics).
//
// Tile: 256 c (M) x 256 b (N), BK=32; 512 threads = 8 waves in (c-half 2) x
// (b-quarter 4); each wave 128x64 via 8x4 grid of 16x16x32 MFMAs.
//
// R2 POST-MORTEM (recorded): launch_bounds(512,4) caps the unified VGPR+AGPR
// file at 128/wave < the 128-reg accumulator + fragments -> scratch spill.
// This tile shape REQUIRES the 256-reg budget => 2 waves/SIMD. Do not retry.
//
// R4 POST-MORTEM (recorded): R0/R1/R3/R4 — four structurally different
// schedules — all ~104-110us / 26% MfmaUtil. Single-mechanism explanation:
// every waitcnt asm carried ::: "memory". A memory-clobbering INLINEASM is
// mayLoad/mayStore to SIInsertWaitcnts, which cannot prove it disjoint from
// the LDS that in-flight global_load_lds DMAs write -> it inserts a FULL
// vmcnt(0) drain before each such asm. Every counted-vmcnt schedule
// degenerated to R0's drain pipeline. m201 (same 256с/8-wave/1-block-CU
// geometry, 62% MfmaUtil, 1563 TF) writes waits with NO clobber and uses the
// builtin s_barrier (no compiler drain before raw s_barrier: m139/m201).
//
// R5 LEVER (single change vs R4): strip "memory" from all in-loop waitcnt
// asm; barrier via __builtin_amdgcn_s_barrier(). Ordering now rests on
// "side-effecting instructions (volatile asm / DMA intrinsic / convergent
// barrier builtin) are never reordered against each other" — the property
// m201's verified template relies on. Rule-#18 sched_barrier(0) retained
// after lgkmcnt(0) (clobber never fixed that hazard; the fence does).
//
// Pipeline (unchanged from R4): depth-3 counted vmcnt, 4 LDS buffers
// (128 KB). Per iter: [vmcnt(8); s_barrier] -> tile t landed in all waves;
// ISSUE(t+3) overwrites buf (t-1)&3 whose readers retired at their own
// lgkmcnt(0) before their barrier. vmcnt counts 4 loads/tile/thread,
// in-order retirement => vmcnt(8) = exactly tiles t+1,t+2 in flight.
// Peel: vm(8),vm(8),vm(4),vm(0).
//
// LDS swizzle (4 slots of 16B per 64B row): phys_slot = k_chunk ^ ((row>>1)&3).
// Writer: global_load_lds dest is linear (HW adds lane*16); the SOURCE k-chunk
// is pre-swizzled per-lane: kcol = ((lane&3) ^ ((lane>>3)&3))*8. Reader adds
// the same involution: slot = (quad ^ ((n15>>1)&3))*8. 2-way bank aliasing =
// free (m136). Verified numerically R2/R3/R4 (absmax unchanged).
//
// XCD swizzle: blockIdx&7 = XCD; c-neighbors (2g,2g+1) sharing a b-tile are
// adjacent ids -> co-resident on one XCD -> L2 captures the pair.
__global__ __launch_bounds__(512, 2) void rbf_fused(
    const unsigned short* __restrict__ locb,  // [C_DIM][F_DIM] bf16 bits
    const unsigned short* __restrict__ xb,    // [B_DIM][F_DIM] bf16 bits
    const float* __restrict__ c2,             // [C_DIM]
    const float* __restrict__ x2,             // [B_DIM]
    const float* __restrict__ scale,          // [C_DIM]
    const float* __restrict__ w,              // [O_DIM][C_DIM]
    float* __restrict__ P) {                  // [NSLICE][B_DIM][O_DIM]
  extern __shared__ unsigned short smem[];
  unsigned short* As = smem;           // 4 x 256x32 = 64 KB (8192 elems/buf)
  unsigned short* Bs = smem + 32768;   // 4 x 256x32 = 64 KB

  const int tid = threadIdx.x;
  const int wave = tid >> 6;
  const int lane = tid & 63;
  const int quad = lane >> 4;
  const int n15 = lane & 15;

  // XCD-aware mapping: g = XCD, cIdx in {2g, 2g+1} fastest, then bIdx.
  const int id = blockIdx.x;
  const int g = id & 7;
  const int j = id >> 3;
  const int cIdx = (g << 1) + (j & 1);  // 0..15
  const int bIdx = j >> 1;              // 0..31
  const int cBase = cIdx << 8;
  const int bBase = bIdx << 8;

  const int wch = wave >> 2;  // c-half 0/1
  const int bq = wave & 3;    // b-quarter 0..3
  const int wcc = wch * 128;  // wave centroid offset in tile
  const int wbb = bq * 64;    // wave batch offset in tile

  float x2v[4];
#pragma unroll
  for (int tj = 0; tj < 4; ++tj) x2v[tj] = x2[bBase + wbb + tj * 16 + n15];

  // Staging: per matrix per tile 16 KB = 2 instructions/thread; instruction c
  // covers rows c*128..c*128+127: row = c*128 + wave*16 + (lane>>2),
  // slot = lane&3. LDS dest base (wave-uniform; HW adds lane*16B):
  // c*4096 + wave*512 elems. Global source pre-swizzled by the slot involution.
  const int kcol = (((lane & 3) ^ ((lane >> 3) & 3)) << 3);  // bf16 elems
  const int rsw = ((quad ^ ((n15 >> 1) & 3)) << 3);          // reader slot elems

  const unsigned short* aPtr[2];
  const unsigned short* bPtr[2];
#pragma unroll
  for (int c = 0; c < 2; ++c) {
    const int row = c * 128 + wave * 16 + (lane >> 2);
    aPtr[c] = locb + (size_t)(cBase + row) * F_DIM + kcol;
    bPtr[c] = xb + (size_t)(bBase + row) * F_DIM + kcol;
  }

  // Per-thread LDS byte offsets of fragment (ti=0 / tj=0, buf 0). AS3 cast
  // yields the raw LDS offset (32-bit) for the asm ds_read address operand.
  const unsigned aBaseOff = (unsigned)(size_t)(
      const __attribute__((address_space(3))) void*)&As[(wcc + n15) * 32 + rsw];
  const unsigned bBaseOff = (unsigned)(size_t)(
      const __attribute__((address_space(3))) void*)&Bs[(wbb + n15) * 32 + rsw];

  // Per-thread per-tile: 4 loads (2 A + 2 B) -> vmcnt counts 4/tile.
  // Issue order within ISSUE is fixed (A0,B0,A1,B1) and tile-ordered across
  // calls, so s_waitcnt vmcnt(4*k) retires whole oldest tiles.
#define ISSUE(p, t)                                                            \
  do {                                                                         \
    _Pragma("unroll") for (int c_ = 0; c_ < 2; ++c_) {                         \
      __builtin_amdgcn_global_load_lds(                                        \
          (const __attribute__((address_space(1))) void*)(aPtr[c_] + (t)*BK),  \
          (__attribute__((address_space(3))) void*)&As[(p)*8192 + c_ * 4096 +  \
                                                       wave * 512],            \
          16, 0, 0);                                                           \
      __builtin_amdgcn_global_load_lds(                                        \
          (const __attribute__((address_space(1))) void*)(bPtr[c_] + (t)*BK),  \
          (__attribute__((address_space(3))) void*)&Bs[(p)*8192 + c_ * 4096 +  \
                                                       wave * 512],            \
          16, 0, 0);                                                           \
    }                                                                          \
  } while (0)

  // 12 asm ds_read_b128 (opaque to the waitcnt pass), explicit counted
  // lgkmcnt(0) WITHOUT memory clobber + sched_barrier(0) (rule #18), 32 MFMA.
  // Fragment strides: buf p = p*16384 B, ti/tj = 1024 B (16 rows x 64 B).
#define COMPUTE(p)                                                             \
  do {                                                                         \
    u32x4 ar[8], br[4];                                                        \
    const unsigned ap_ = aBaseOff + (unsigned)(p)*16384u;                      \
    const unsigned bp_ = bBaseOff + (unsigned)(p)*16384u;                      \
    _Pragma("unroll") for (int ti_ = 0; ti_ < 8; ++ti_)                        \
        asm volatile("ds_read_b128 %0, %1"                                     \
                     : "=v"(ar[ti_])                                           \
                     : "v"(ap_ + (unsigned)(ti_ * 1024)));                     \
    _Pragma("unroll") for (int tj_ = 0; tj_ < 4; ++tj_)                        \
        asm volatile("ds_read_b128 %0, %1"                                     \
                     : "=v"(br[tj_])                                           \
                     : "v"(bp_ + (unsigned)(tj_ * 1024)));                     \
    asm volatile("s_waitcnt lgkmcnt(0)");                                      \
    __builtin_amdgcn_sched_barrier(0);                                         \
    __builtin_amdgcn_s_setprio(1);                                             \
    _Pragma("unroll") for (int ti_ = 0; ti_ < 8; ++ti_)                        \
        _Pragma("unroll") for (int tj_ = 0; tj_ < 4; ++tj_)                    \
            acc[ti_][tj_] = __builtin_amdgcn_mfma_f32_16x16x32_bf16(           \
                __builtin_bit_cast(bf16x8, ar[ti_]),                           \
                __builtin_bit_cast(bf16x8, br[tj_]), acc[ti_][tj_], 0, 0, 0);  \
    __builtin_amdgcn_s_setprio(0);                                             \
  } while (0)

  // Counted wait (NO memory clobber -> no compiler-inserted vmcnt(0) drain)
  // + raw builtin barrier (no drain before raw s_barrier: m139/m201).
#define WAITB(n)                                                               \
  do {                                                                         \
    asm volatile("s_waitcnt vmcnt(" #n ")");                                   \
    __builtin_amdgcn_s_barrier();                                              \
  } while (0)

  f32x4 acc[8][4];
  const f32x4 zero = {0.f, 0.f, 0.f, 0.f};
#pragma unroll
  for (int i = 0; i < 8; ++i)
#pragma unroll
    for (int jj = 0; jj < 4; ++jj) acc[i][jj] = zero;

  // Depth-3 pipeline prologue: tiles 0,1,2 -> bufs 0,1,2.
  ISSUE(0, 0);
  ISSUE(1, 1);
  ISSUE(2, 2);
  for (int t = 0; t < 29; ++t) {
    WAITB(8);                    // tile t landed; t+1,t+2 stay in flight
    ISSUE((t + 3) & 3, t + 3);   // overwrites buf (t-1)&3: readers retired
    COMPUTE(t & 3);
  }
  WAITB(8);
  COMPUTE(1);  // t = 29
  WAITB(4);
  COMPUTE(2);  // t = 30
  WAITB(0);
  COMPUTE(3);  // t = 31
  __syncthreads();  // full-drain boundary before epilogue LDS reuse

  // ---- epilogue ----
  // acc[ti][tj][r]: c_local = wcc+ti*16+quad*4+r, b_local = wbb+tj*16+n15.
  // Stage w / c2 / (-1/scale) into the dead As region (64 KB avail).
  float* wlds = reinterpret_cast<float*>(As);  // [O_DIM*256] = 10 KB
  float* c2l = wlds + O_DIM * 256;             // [256]
  float* nisl = c2l + 256;                     // [256]
  for (int i = tid; i < O_DIM * 256; i += 512)
    wlds[i] = w[(i >> 8) * C_DIM + cBase + (i & 255)];
  if (tid < 256) {
    c2l[tid] = c2[cBase + tid];
    nisl[tid] = -1.0f / scale[cBase + tid];
  }
  __syncthreads();

  float partial[4][O_DIM];
#pragma unroll
  for (int tj = 0; tj < 4; ++tj)
#pragma unroll
    for (int o = 0; o < O_DIM; ++o) partial[tj][o] = 0.f;

#pragma unroll
  for (int ti = 0; ti < 8; ++ti) {
    const int clq = wcc + ti * 16 + quad * 4;
    const f32x4 c24 = *(const f32x4*)&c2l[clq];
    const f32x4 ns4 = *(const f32x4*)&nisl[clq];
    float phi[4][4];  // [tj][r]
#pragma unroll
    for (int tj = 0; tj < 4; ++tj)
#pragma unroll
      for (int r = 0; r < 4; ++r) {
        const float s = acc[ti][tj][r];
        const float sq = fmaxf(x2v[tj] + c24[r] - 2.0f * s, 0.0f);
        phi[tj][r] = __expf(sqrtf(sq) * ns4[r]);
      }
#pragma unroll
    for (int o = 0; o < O_DIM; ++o) {
      const f32x4 w4 = *(const f32x4*)&wlds[o * 256 + clq];
#pragma unroll
      for (int tj = 0; tj < 4; ++tj)
#pragma unroll
        for (int r = 0; r < 4; ++r)
          partial[tj][o] = fmaf(phi[tj][r], w4[r], partial[tj][o]);
    }
  }

  // reduce over the 4 quads (lanes ^16, ^32 share the same batch index)
#pragma unroll
  for (int tj = 0; tj < 4; ++tj)
#pragma unroll
    for (int o = 0; o < O_DIM; ++o) {
      float v = partial[tj][o];
      v += __shfl_xor(v, 16, 64);
      v += __shfl_xor(v, 32, 64);
      partial[tj][o] = v;
    }

  // Cross-wave (c-halves) reduce via LDS (alias dead Bs), then store.
  float* red = reinterpret_cast<float*>(Bs);  // 2560 floats, region is dead
  if (wch == 0 && quad == 0) {
#pragma unroll
    for (int tj = 0; tj < 4; ++tj)
#pragma unroll
      for (int o = 0; o < O_DIM; ++o)
        red[(wbb + tj * 16 + n15) * O_DIM + o] = partial[tj][o];
  }
  __syncthreads();
  if (wch == 1 && quad == 0) {
#pragma unroll
    for (int tj = 0; tj < 4; ++tj)
#pragma unroll
      for (int o = 0; o < O_DIM; ++o)
        red[(wbb + tj * 16 + n15) * O_DIM + o] += partial[tj][o];
  }
  __syncthreads();
  float* Pdst = P + (size_t)cIdx * (B_DIM * O_DIM) + (size_t)bBase * O_DIM;
  for (int i = tid; i < 256 * O_DIM; i += 512) Pdst[i] = red[i];
}

// ---------------------------------------------------------------------------
// out[b][o] = sum_k P[k][b][o]
__global__ __launch_bounds__(256) void reduce_partials(const float* __restrict__ P,
                                                       float* __restrict__ out) {
  const int i = blockIdx.x * 256 + threadIdx.x;  // 0 .. B_DIM*O_DIM-1
  float s = 0.f;
#pragma unroll
  for (int k = 0; k < NSLICE; ++k) s += P[(size_t)k * (B_DIM * O_DIM) + i];
  out[i] = s;
}

// ---------------------------------------------------------------------------
extern "C" void kernel_launch(void* const* d_in, const int* in_sizes, int n_in,
                              void* d_out, int out_size, void* d_ws, size_t ws_size,
                              hipStream_t stream) {
  const float* x = (const float*)d_in[0];      // [8192,1024]
  const float* loc = (const float*)d_in[1];    // [4096,1024]
  const float* scale = (const float*)d_in[2];  // [4096]
  const float* w = (const float*)d_in[3];      // [10,4096]
  float* out = (float*)d_out;                  // [8192,10]

  // workspace layout (~30.3 MB)
  char* ws = (char*)d_ws;
  unsigned short* xb = (unsigned short*)(ws);                              // 16 MB
  unsigned short* locb = (unsigned short*)(ws + (size_t)16 * 1024 * 1024); // 8 MB
  float* x2 = (float*)(ws + (size_t)24 * 1024 * 1024);                    // 32 KB
  float* c2 = (float*)(ws + (size_t)24 * 1024 * 1024 + 64 * 1024);        // 16 KB
  float* P = (float*)(ws + (size_t)25 * 1024 * 1024);                     // 5.24 MB

  // 128 KB dynamic LDS (static cap is 64 KB). Host-side attribute set;
  // idempotent, not a stream op — safe under graph capture.
  hipFuncSetAttribute((const void*)rbf_fused,
                      hipFuncAttributeMaxDynamicSharedMemorySize, 131072);

  prep_merged<<<(B_DIM + C_DIM) / 8, 512, 0, stream>>>(x, loc, xb, locb, x2, c2);

  rbf_fused<<<NSLICE * 32, 512, 131072, stream>>>(locb, xb, c2, x2, scale, w, P);

  reduce_partials<<<(B_DIM * O_DIM) / 256, 256, 0, stream>>>(P, out);
}